// Round 1
// baseline (252.926 us; speedup 1.0000x reference)
//
#include <hip/hip_runtime.h>

// Patch_Embed_Center_Rotate: x (256,3,224,224) f32, P=16, grid 14x14.
// out = x everywhere, except patches with grid col j in [5,9] AND grid row
// k in [5,9], which are transposed within the 16x16 patch:
//   out[b,c, k*16+a3, j*16+a4] = x[b,c, k*16+a4, j*16+a3]
// Memory-bound copy (~294 MB round trip). One thread per output float4.

#define HH 224
#define WW 224
#define W4 56  // 224/4

__global__ __launch_bounds__(256) void patch_rotate_kernel(
    const float* __restrict__ x, float* __restrict__ out, int n4) {
  int idx = blockIdx.x * blockDim.x + threadIdx.x;  // float4 index into out
  if (idx >= n4) return;

  int bc   = idx / (HH * W4);   // fused (b,c)
  int rem  = idx % (HH * W4);
  int row  = rem / W4;          // 0..223
  int col4 = rem % W4;          // 0..55

  int k = row >> 4;     // grid row
  int j = col4 >> 2;    // grid col  (col4*4/16)

  bool center = (j >= 5) & (j <= 9) & (k >= 5) & (k <= 9);

  float4 v;
  if (!center) {
    v = ((const float4*)x)[idx];          // identity, fully coalesced
  } else {
    // transposed patch: out col a4 -> src row k*16+a4; out row a3 -> src col
    int a3  = row & 15;
    int a4b = (col4 & 3) << 2;            // first of 4 a4 values
    int base = (bc * HH + (k << 4)) * WW + (j << 4) + a3;  // a4 = 0 element
    v.x = x[base + (a4b + 0) * WW];
    v.y = x[base + (a4b + 1) * WW];
    v.z = x[base + (a4b + 2) * WW];
    v.w = x[base + (a4b + 3) * WW];
  }
  ((float4*)out)[idx] = v;
}

extern "C" void kernel_launch(void* const* d_in, const int* in_sizes, int n_in,
                              void* d_out, int out_size, void* d_ws, size_t ws_size,
                              hipStream_t stream) {
  const float* x = (const float*)d_in[0];
  float* out = (float*)d_out;
  int n4 = out_size / 4;                       // 9,633,792 float4s
  int threads = 256;
  int blocks = (n4 + threads - 1) / threads;   // 37,632
  patch_rotate_kernel<<<blocks, threads, 0, stream>>>(x, out, n4);
}